// Round 9
// baseline (6118.631 us; speedup 1.0000x reference)
//
#include <hip/hip_runtime.h>
#include <cstddef>
#include <cstdint>

typedef unsigned long long ull;
typedef unsigned short u16;
typedef __attribute__((ext_vector_type(8))) short s8v;   // 8 x bf16 (MFMA A/B frag)
typedef __attribute__((ext_vector_type(4))) float f4v;   // MFMA C/D frag

#define GROUPS 8
#define BG     16
#define JS     16
#define TPB    256
#define NT     1024
#define HDIM   512
#define INDIM  17
#define OUTDIM 17
#define BTOT   128

// Cross-WG traffic: relaxed agent-scope atomics (sc1 -> MALL). No fences.
#define AT_LD(p)   __hip_atomic_load((p), __ATOMIC_RELAXED, __HIP_MEMORY_SCOPE_AGENT)
#define AT_ST(p,v) __hip_atomic_store((p), (v), __ATOMIC_RELAXED, __HIP_MEMORY_SCOPE_AGENT)

// frag-order plane (bf16 hi only now): 16b x 512k
// u16 idx(k,b) = (k>>5)*512 + ((k>>3)&3)*128 + b*8 + (k&7)
// WG wg's j-slice = contiguous 256-u16 block at SLICE(wg).
// First half-plane (u16 [0,4096)) = producers wg 0..15; second = wg 16..31.
#define TILE_U16 8192
#define WIDX(k, b) ((((k) >> 5) * 512) + ((((k) >> 3) & 3) * 128) + ((b) * 8) + ((k) & 7))
#define SLICE(wg)  (((wg) >> 1) * 512 + ((wg) & 1) * 256)

// ---------------- workspace ----------------
#define FA_OFF     ((size_t)0)                         // 8 groups x 32 ints = 1 KB
#define FB_OFF     ((size_t)1024)
#define RA_OFF     ((size_t)4096)
#define RING_BYTES ((size_t)4 * GROUPS * TILE_U16 * 2) // 4-slot ring, single plane, 512 KB
#define RB_OFF     (RA_OFF + RING_BYTES)
#define FB32_OFF   (RB_OFF + RING_BYTES)               // fp32 h1[NT]: 128x512x4 = 256 KB
#define WS_NEEDED  (FB32_OFF + (size_t)BTOT * HDIM * 4)
#define RIX1(sl, gr) (((size_t)(sl) * GROUPS + (gr)) * TILE_U16)

// ---------------- LDS layout ----------------
#define L_H0   0                        // h0 stage ring: 3 slots x 16 KB (hi plane)
#define L_H1   49152                    // h1 stage: 16 KB
#define L_EXA  65536                    // gate exchange L0, 4 KB
#define L_EXB  69632                    // gate exchange L1, 4 KB
#define L_HOA  73728                    // h out staging L0: 512 B
#define L_HOB  74240                    // h out staging L1: 512 B
#define L_CTL  74752                    // control ints (64 B)
#define LDS_SZ 74816
// ctl: 0=ctrA 1=ctrB 4..6=stage_ready[3] 7=L1 progress (back-pressure)

__device__ __forceinline__ u16 f2bf(float f) {
  unsigned int u = __float_as_uint(f);
  u += 0x7FFFu + ((u >> 16) & 1u);
  return (u16)(u >> 16);
}
__device__ __forceinline__ float bf2f(u16 h) {
  return __uint_as_float(((unsigned int)h) << 16);
}
__device__ __forceinline__ float sigm(float x) { return 1.f / (1.f + __expf(-x)); }
__device__ __forceinline__ float tanh_f(float x) { return 2.f / (1.f + __expf(-2.f * x)) - 1.f; }

#define MFMA(a, b, c) __builtin_amdgcn_mfma_f32_16x16x32_bf16((a), (b), (c), 0, 0, 0)

// 2-wave pair barrier via LDS monotonic counter (lane0 adds, all spin)
__device__ __forceinline__ void pbar(int* c, int& nbar, int lane) {
  ++nbar;
  if (lane == 0)
    (void)__hip_atomic_fetch_add(c, 1, __ATOMIC_RELEASE, __HIP_MEMORY_SCOPE_WORKGROUP);
  while (__hip_atomic_load(c, __ATOMIC_ACQUIRE, __HIP_MEMORY_SCOPE_WORKGROUP) < 2 * nbar) {}
}

// ---------------- fused 2-layer persistent LSTM, wave-specialized ----------------
// 256 WGs (1/CU). gr = bid&7 owns batches [gr*16,..); wg = bid>>3 owns j-slice.
// Waves 0-1 = L0 pipeline; waves 2-3 = L1 pipeline. h comm is bf16 (hi) only;
// cell state fp32 in regs; h1[NT] additionally published fp32 for the output
// layer. Each pipeline wave polls only the 16 producer flags covering the
// half-plane it stages. L0's LDS-ring back-pressure reads a local ctl word
// (set by L1) instead of polling flagB through MALL.
__global__ __launch_bounds__(TPB, 1) void lstm_fused(
    const float* __restrict__ x,
    const float* __restrict__ wih0, const float* __restrict__ whh0,
    const float* __restrict__ bih0, const float* __restrict__ bhh0,
    const float* __restrict__ wih1, const float* __restrict__ whh1,
    const float* __restrict__ bih1, const float* __restrict__ bhh1,
    u16* __restrict__ ringA, u16* __restrict__ ringB,
    float* __restrict__ fb32,
    int* __restrict__ flagsA, int* __restrict__ flagsB)
{
  const int bid  = blockIdx.x;
  const int gr   = bid & 7;
  const int wg   = bid >> 3;
  const int j0   = wg * JS;
  const int tid  = threadIdx.x;
  const int wave = tid >> 6;
  const int lane = tid & 63;
  const int n    = lane & 15;        // A-frag row (batch) / B-frag col (j)
  const int q    = lane >> 4;        // k-sub-quad
  const int k0   = q * 8;

  __shared__ __align__(16) char smem[LDS_SZ];
  int* ctl = (int*)(smem + L_CTL);
  float* exgA = (float*)(smem + L_EXA);
  float* exgB = (float*)(smem + L_EXB);

  if (tid < 8) ctl[tid] = 0;

  // ---- init ring slot 0 = zeros (own slice), then publish flags = 1 ----
  {
    int b_l = tid >> 4, j_l = tid & 15, jg = j0 + j_l;
    int wo = WIDX(jg, b_l);
    AT_ST(&ringA[RIX1(0, gr) + wo], (u16)0);
    AT_ST(&ringB[RIX1(0, gr) + wo], (u16)0);
  }
  __syncthreads();  // full drain before flags; only __syncthreads in kernel
  if (wave == 0 && lane == 0) AT_ST(flagsA + gr * 32 + wg, 1);
  if (wave == 2 && lane == 0) AT_ST(flagsB + gr * 32 + wg, 1);

  const f4v z = {0.f, 0.f, 0.f, 0.f};
  const int p  = (wave & 1) * 64 + lane;  // pair-tid 0..127
  const int jq = p & 15, b0 = p >> 4;     // cells (b0,jq) and (b0+8,jq)
  const int jg = j0 + jq;
  const int ho0 = (jq >> 3) * 128 + b0 * 8 + (jq & 7);        // hout u16 idx
  const int ho1 = (jq >> 3) * 128 + (b0 + 8) * 8 + (jq & 7);
  const int slice = SLICE(wg);
  const int half = wave & 1;              // which half-plane this wave stages

  if (wave < 2) {
    // ================= L0 pipeline (waves 0,1) =================
    const int g0 = wave * 2;  // gates g0, g0+1 (full K)
    s8v wx_h[2], wx_l[2];
#pragma unroll
    for (int i = 0; i < 2; ++i) {
      const float* wr = wih0 + (size_t)((g0 + i) * HDIM + j0 + n) * INDIM;
#pragma unroll
      for (int j = 0; j < 8; ++j) {
        int k = k0 + j;
        float v = (k < INDIM) ? wr[k] : 0.f;
        u16 hi = f2bf(v);
        wx_h[i][j] = (short)hi;
        wx_l[i][j] = (short)f2bf(v - bf2f(hi));
      }
    }
    s8v wh_h[2][16], wh_l[2][16];
#pragma unroll
    for (int i = 0; i < 2; ++i) {
      const float* wr = whh0 + (size_t)((g0 + i) * HDIM + j0 + n) * HDIM;
#pragma unroll
      for (int kt = 0; kt < 16; ++kt)
#pragma unroll
        for (int j = 0; j < 8; ++j) {
          float v = wr[kt * 32 + k0 + j];
          u16 hi = f2bf(v);
          wh_h[i][kt][j] = (short)hi;
          wh_l[i][kt][j] = (short)f2bf(v - bf2f(hi));
        }
    }
    float bias[4];
#pragma unroll
    for (int g = 0; g < 4; ++g) bias[g] = bih0[g * HDIM + jg] + bhh0[g * HDIM + jg];
    float c0a = 0.f, c0b = 0.f;
    int nbar = 0;

    for (int s = 1; s <= NT + 1; ++s) {
      // x-part (no peer dependency): before the wait
      f4v xa[2] = {z, z};
      if (s <= NT) {
        const float* xr = x + ((size_t)(gr * BG + n) * NT + (s - 1)) * INDIM;
        s8v axh, axl;
#pragma unroll
        for (int j = 0; j < 8; ++j) {
          int k = k0 + j;
          float v = (k < INDIM) ? xr[k] : 0.f;
          u16 hi = f2bf(v);
          axh[j] = (short)hi;
          axl[j] = (short)f2bf(v - bf2f(hi));
        }
#pragma unroll
        for (int i = 0; i < 2; ++i) {
          xa[i] = MFMA(axh, wx_h[i], xa[i]);
          xa[i] = MFMA(axl, wx_h[i], xa[i]);
          xa[i] = MFMA(axh, wx_l[i], xa[i]);
        }
      }
      // poll own 16 producer flags (4 lanes per flag) + local back-pressure:
      // L1 must have finished step s-4 before we overwrite LDS slot (s-1)%3
      {
        const int* pp = flagsA + gr * 32 + half * 16 + (lane & 15);
        for (;;) {
          bool ok = AT_LD(pp) >= s;
          int l1t = __hip_atomic_load(&ctl[7], __ATOMIC_ACQUIRE,
                                      __HIP_MEMORY_SCOPE_WORKGROUP);
          if (__ballot(ok) == ~0ULL && l1t >= s - 4) break;
          __builtin_amdgcn_s_sleep(1);
        }
      }
      // stage own half of h0[s-1]: ringA slot (s-1)&3 -> LDS slot (s-1)%3
      const int sl3 = (s - 1) % 3;
      {
        const ull* src = (const ull*)(ringA + RIX1((s - 1) & 3, gr)) + half * 1024;
        char* dst = smem + L_H0 + sl3 * 16384 + half * 8192;
        ull v[16];
#pragma unroll
        for (int i = 0; i < 16; ++i) v[i] = AT_LD(src + i * 64 + lane);
#pragma unroll
        for (int i = 0; i < 16; ++i) *(ull*)(dst + (i * 64 + lane) * 8) = v[i];
      }
      pbar(&ctl[0], nbar, lane);                              // P1: stage visible
      if (wave == 0 && lane == 0)
        __hip_atomic_store(&ctl[4 + sl3], s - 1, __ATOMIC_RELEASE,
                           __HIP_MEMORY_SCOPE_WORKGROUP);
      if (s == NT + 1) break;  // tail step only feeds L1's last x-input

      // K-loop: 16 ds_read_b128 + 64 MFMA (2 gates x 16kt x {Wh,Wl})
      const char* sh = smem + L_H0 + sl3 * 16384;
      f4v cHH[2] = {z, z}, cHL[2] = {z, z};
#pragma unroll
      for (int kt = 0; kt < 16; ++kt) {
        s8v ah = *(const s8v*)(sh + kt * 1024 + q * 256 + n * 16);
#pragma unroll
        for (int i = 0; i < 2; ++i) {
          cHH[i] = MFMA(ah, wh_h[i][kt], cHH[i]);
          cHL[i] = MFMA(ah, wh_l[i][kt], cHL[i]);
        }
      }
#pragma unroll
      for (int i = 0; i < 2; ++i) {
        f4v e = xa[i] + cHH[i] + cHL[i];
#pragma unroll
        for (int r = 0; r < 4; ++r)
          exgA[(g0 + i) * 256 + (q * 4 + r) * 16 + n] = e[r];
      }
      pbar(&ctl[0], nbar, lane);                              // P2: preacts ready
      // elementwise: 2 cells/thread -> write h (bf16) into LDS hout
      u16* ho = (u16*)(smem + L_HOA);
      {
        float pi = exgA[0 * 256 + b0 * 16 + jq] + bias[0];
        float pf = exgA[1 * 256 + b0 * 16 + jq] + bias[1];
        float pg = exgA[2 * 256 + b0 * 16 + jq] + bias[2];
        float po = exgA[3 * 256 + b0 * 16 + jq] + bias[3];
        float ig = sigm(pi), fg = sigm(pf), gg = tanh_f(pg), og = sigm(po);
        c0a = fg * c0a + ig * gg;
        ho[ho0] = f2bf(og * tanh_f(c0a));
      }
      {
        float pi = exgA[0 * 256 + (b0 + 8) * 16 + jq] + bias[0];
        float pf = exgA[1 * 256 + (b0 + 8) * 16 + jq] + bias[1];
        float pg = exgA[2 * 256 + (b0 + 8) * 16 + jq] + bias[2];
        float po = exgA[3 * 256 + (b0 + 8) * 16 + jq] + bias[3];
        float ig = sigm(pi), fg = sigm(pf), gg = tanh_f(pg), og = sigm(po);
        c0b = fg * c0b + ig * gg;
        ho[ho1] = f2bf(og * tanh_f(c0b));
      }
      pbar(&ctl[0], nbar, lane);                              // P3: hout complete
      if (wave == 0) {                 // lead wave: coalesced publish + flag
        ull v0 = *(const ull*)(smem + L_HOA + lane * 8);
        ull* d0 = (ull*)ringA + ((RIX1(s & 3, gr) + slice) >> 2);
        AT_ST(d0 + lane, v0);
        __asm__ volatile("s_waitcnt vmcnt(0)" ::: "memory");
        if (lane == 0) AT_ST(flagsA + gr * 32 + wg, s + 1);
      }
    }
  } else {
    // ================= L1 pipeline (waves 2,3) =================
    const int g0 = (wave - 2) * 2;  // gates g0, g0+1; wih1/whh1 hi-only
    s8v w1x[2][16], w1h[2][16];
#pragma unroll
    for (int i = 0; i < 2; ++i) {
      const float* p1 = wih1 + (size_t)((g0 + i) * HDIM + j0 + n) * HDIM;
      const float* p2 = whh1 + (size_t)((g0 + i) * HDIM + j0 + n) * HDIM;
#pragma unroll
      for (int kt = 0; kt < 16; ++kt)
#pragma unroll
        for (int j = 0; j < 8; ++j) {
          w1x[i][kt][j] = (short)f2bf(p1[kt * 32 + k0 + j]);
          w1h[i][kt][j] = (short)f2bf(p2[kt * 32 + k0 + j]);
        }
    }
    float bias[4];
#pragma unroll
    for (int g = 0; g < 4; ++g) bias[g] = bih1[g * HDIM + jg] + bhh1[g * HDIM + jg];
    float c1a = 0.f, c1b = 0.f;
    int nbar = 0;

    for (int t = 1; t <= NT; ++t) {
      // poll own 16 producer flags (4 lanes per flag)
      {
        const int* pp = flagsB + gr * 32 + half * 16 + (lane & 15);
        while (__ballot(AT_LD(pp) >= t) != ~0ULL) __builtin_amdgcn_s_sleep(1);
      }
      // stage own half of h1[t-1]: ringB slot (t-1)&3 -> LDS
      {
        const ull* src = (const ull*)(ringB + RIX1((t - 1) & 3, gr)) + half * 1024;
        char* dst = smem + L_H1 + half * 8192;
        ull v[16];
#pragma unroll
        for (int i = 0; i < 16; ++i) v[i] = AT_LD(src + i * 64 + lane);
#pragma unroll
        for (int i = 0; i < 16; ++i) *(ull*)(dst + (i * 64 + lane) * 8) = v[i];
      }
      pbar(&ctl[1], nbar, lane);                              // Q1: h1 staged
      // K-loop B: h1 recurrence
      const char* th = smem + L_H1;
      f4v dHH[2] = {z, z};
#pragma unroll
      for (int kt = 0; kt < 16; ++kt) {
        s8v ah = *(const s8v*)(th + kt * 1024 + q * 256 + n * 16);
#pragma unroll
        for (int i = 0; i < 2; ++i) dHH[i] = MFMA(ah, w1h[i][kt], dHH[i]);
      }
      // wait for local L0's LDS stage of h0[t] (our x-input)
      const int sl3 = t % 3;
      while (__hip_atomic_load(&ctl[4 + sl3], __ATOMIC_ACQUIRE,
                               __HIP_MEMORY_SCOPE_WORKGROUP) < t) {}
      const char* sh = smem + L_H0 + sl3 * 16384;
      f4v eHH[2] = {z, z};
#pragma unroll
      for (int kt = 0; kt < 16; ++kt) {
        s8v ah = *(const s8v*)(sh + kt * 1024 + q * 256 + n * 16);
#pragma unroll
        for (int i = 0; i < 2; ++i) eHH[i] = MFMA(ah, w1x[i][kt], eHH[i]);
      }
#pragma unroll
      for (int i = 0; i < 2; ++i) {
        f4v e = dHH[i] + eHH[i];
#pragma unroll
        for (int r = 0; r < 4; ++r)
          exgB[(g0 + i) * 256 + (q * 4 + r) * 16 + n] = e[r];
      }
      pbar(&ctl[1], nbar, lane);                              // Q2: preacts ready
      u16* ho = (u16*)(smem + L_HOB);
      {
        float pi = exgB[0 * 256 + b0 * 16 + jq] + bias[0];
        float pf = exgB[1 * 256 + b0 * 16 + jq] + bias[1];
        float pg = exgB[2 * 256 + b0 * 16 + jq] + bias[2];
        float po = exgB[3 * 256 + b0 * 16 + jq] + bias[3];
        float ig = sigm(pi), fg = sigm(pf), gg = tanh_f(pg), og = sigm(po);
        c1a = fg * c1a + ig * gg;
        float h = og * tanh_f(c1a);
        ho[ho0] = f2bf(h);
        if (t == NT)
          AT_ST((unsigned int*)&fb32[(size_t)(gr * BG + b0) * HDIM + jg],
                __float_as_uint(h));
      }
      {
        float pi = exgB[0 * 256 + (b0 + 8) * 16 + jq] + bias[0];
        float pf = exgB[1 * 256 + (b0 + 8) * 16 + jq] + bias[1];
        float pg = exgB[2 * 256 + (b0 + 8) * 16 + jq] + bias[2];
        float po = exgB[3 * 256 + (b0 + 8) * 16 + jq] + bias[3];
        float ig = sigm(pi), fg = sigm(pf), gg = tanh_f(pg), og = sigm(po);
        c1b = fg * c1b + ig * gg;
        float h = og * tanh_f(c1b);
        ho[ho1] = f2bf(h);
        if (t == NT)
          AT_ST((unsigned int*)&fb32[(size_t)(gr * BG + b0 + 8) * HDIM + jg],
                __float_as_uint(h));
      }
      pbar(&ctl[1], nbar, lane);                              // Q3: hout complete
      if (wave == 2) {                 // lead wave: coalesced publish + flag
        ull v0 = *(const ull*)(smem + L_HOB + lane * 8);
        ull* d0 = (ull*)ringB + ((RIX1(t & 3, gr) + slice) >> 2);
        AT_ST(d0 + lane, v0);
        __asm__ volatile("s_waitcnt vmcnt(0)" ::: "memory");
        if (lane == 0) {
          AT_ST(flagsB + gr * 32 + wg, t + 1);
          __hip_atomic_store(&ctl[7], t, __ATOMIC_RELEASE,
                             __HIP_MEMORY_SCOPE_WORKGROUP);  // local back-pressure
        }
      }
    }
  }
}

// ---------------- final linear: out = h1[NT] @ lin_w^T + lin_b (fp32 h) ------
__global__ void final_linear(const float* __restrict__ fb32,
                             const float* __restrict__ lin_w,
                             const float* __restrict__ lin_b,
                             float* __restrict__ out) {
  int b = blockIdx.x, o = threadIdx.x;
  if (o < OUTDIM) {
    float acc = lin_b[o];
    const float* hr = fb32 + (size_t)b * HDIM;
    for (int j = 0; j < HDIM; ++j) acc += hr[j] * lin_w[(size_t)o * HDIM + j];
    out[b * OUTDIM + o] = acc;
  }
}

__global__ void init_flags(int* __restrict__ f) {
  int i = blockIdx.x * TPB + threadIdx.x;
  if (i < 512) f[i] = 0;   // flagsA (256) + flagsB (256) contiguous
}

__global__ void sentinel_kernel(float* __restrict__ out, int nv) {
  int i = blockIdx.x * TPB + threadIdx.x;
  if (i < nv) out[i] = 1e30f;
}

extern "C" void kernel_launch(void* const* d_in, const int* in_sizes, int n_in,
                              void* d_out, int out_size, void* d_ws, size_t ws_size,
                              hipStream_t stream) {
  (void)in_sizes; (void)n_in;
  const float* x     = (const float*)d_in[0];
  const float* wih0  = (const float*)d_in[1];
  const float* whh0  = (const float*)d_in[2];
  const float* bih0  = (const float*)d_in[3];
  const float* bhh0  = (const float*)d_in[4];
  const float* wih1  = (const float*)d_in[5];
  const float* whh1  = (const float*)d_in[6];
  const float* bih1  = (const float*)d_in[7];
  const float* bhh1  = (const float*)d_in[8];
  const float* lin_w = (const float*)d_in[9];
  const float* lin_b = (const float*)d_in[10];
  float* out = (float*)d_out;
  char* ws = (char*)d_ws;

  if (ws_size < WS_NEEDED) {
    sentinel_kernel<<<(out_size + TPB - 1) / TPB, TPB, 0, stream>>>(out, out_size);
    return;
  }

  int* flagsA = (int*)(ws + FA_OFF);
  int* flagsB = (int*)(ws + FB_OFF);
  u16* ringA  = (u16*)(ws + RA_OFF);
  u16* ringB  = (u16*)(ws + RB_OFF);
  float* fb32 = (float*)(ws + FB32_OFF);

  init_flags<<<2, TPB, 0, stream>>>(flagsA);
  lstm_fused<<<256, TPB, 0, stream>>>(x, wih0, whh0, bih0, bhh0,
                                      wih1, whh1, bih1, bhh1,
                                      ringA, ringB, fb32, flagsA, flagsB);
  final_linear<<<BTOT, 64, 0, stream>>>(fb32, lin_w, lin_b, out);
}

// Round 10
// 4737.554 us; speedup vs baseline: 1.2915x; 1.2915x over previous
//
#include <hip/hip_runtime.h>
#include <cstddef>
#include <cstdint>

typedef unsigned long long ull;
typedef unsigned short u16;
typedef unsigned int u32;
typedef __attribute__((ext_vector_type(8))) short s8v;   // 8 x bf16 (MFMA A/B frag)
typedef __attribute__((ext_vector_type(4))) float f4v;   // MFMA C/D frag

#define GROUPS 8
#define BG     16
#define JS     16
#define TPB    256
#define NT     1024
#define HDIM   512
#define INDIM  17
#define OUTDIM 17
#define BTOT   128

// Cross-WG traffic: relaxed agent-scope atomics (sc1 -> MALL). No fences, no flags.
#define AT_LD(p)   __hip_atomic_load((p), __ATOMIC_RELAXED, __HIP_MEMORY_SCOPE_AGENT)
#define AT_ST(p,v) __hip_atomic_store((p), (v), __ATOMIC_RELAXED, __HIP_MEMORY_SCOPE_AGENT)

// frag-order plane, u32 elements: entry = (step_tag << 16) | bf16_h.
// u32 idx(k,b) = (k>>5)*512 + ((k>>3)&3)*128 + b*8 + (k&7); plane = 8192 u32 = 32KB.
// Tag+value share one u32 -> one 8B atomic load can never tear them apart.
#define PLANE32 8192
#define WIDX(k, b) ((((k) >> 5) * 512) + ((((k) >> 3) & 3) * 128) + ((b) * 8) + ((k) & 7))
#define SLICE(wg)  (((wg) >> 1) * 512 + ((wg) & 1) * 256)   // WG's contiguous 256-u32 slice

// ---------------- workspace ----------------
#define RA_OFF     ((size_t)0)
#define RING_BYTES ((size_t)4 * GROUPS * PLANE32 * 4)   // 4-slot ring, 1 MB
#define RB_OFF     (RA_OFF + RING_BYTES)
#define FB32_OFF   (RB_OFF + RING_BYTES)                // fp32 h1[NT]: 256 KB
#define WS_NEEDED  (FB32_OFF + (size_t)BTOT * HDIM * 4)
#define RIX32(sl, gr) (((size_t)(sl) * GROUPS + (gr)) * PLANE32)

// ---------------- LDS layout ----------------
#define L_H0   0                        // h0 stage ring: 3 slots x 16 KB (u16 frag-order)
#define L_H1   49152                    // h1 stage: 16 KB
#define L_EXA  65536                    // gate exchange L0, 4 KB
#define L_EXB  69632                    // gate exchange L1, 4 KB
#define L_HOA  73728                    // h out staging L0: 256 u32 = 1 KB
#define L_HOB  74752                    // h out staging L1: 1 KB
#define L_CTL  75776                    // control ints (64 B)
#define LDS_SZ 75840
// ctl: 0=ctrA 1=ctrB 4..6=stage_ready[3] 7=L1 progress (back-pressure)

__device__ __forceinline__ u16 f2bf(float f) {
  unsigned int u = __float_as_uint(f);
  u += 0x7FFFu + ((u >> 16) & 1u);
  return (u16)(u >> 16);
}
__device__ __forceinline__ float bf2f(u16 h) {
  return __uint_as_float(((unsigned int)h) << 16);
}
__device__ __forceinline__ float sigm(float x) { return 1.f / (1.f + __expf(-x)); }
__device__ __forceinline__ float tanh_f(float x) { return 2.f / (1.f + __expf(-2.f * x)) - 1.f; }

#define MFMA(a, b, c) __builtin_amdgcn_mfma_f32_16x16x32_bf16((a), (b), (c), 0, 0, 0)

// 2-wave pair barrier via LDS monotonic counter (lane0 adds, all spin)
__device__ __forceinline__ void pbar(int* c, int& nbar, int lane) {
  ++nbar;
  if (lane == 0)
    (void)__hip_atomic_fetch_add(c, 1, __ATOMIC_RELEASE, __HIP_MEMORY_SCOPE_WORKGROUP);
  while (__hip_atomic_load(c, __ATOMIC_ACQUIRE, __HIP_MEMORY_SCOPE_WORKGROUP) < 2 * nbar) {}
}

// ---------------- fused 2-layer persistent LSTM, tag-in-data sync ---------------
// 256 WGs (1/CU). gr = bid&7 owns batches [gr*16,..); wg = bid>>3 owns j-slice.
// Waves 0-1 = L0 pipeline; waves 2-3 = L1. h comm = (tag<<16|bf16) u32 via MALL;
// consumers poll the data itself (no flags, no drains). Proof of slot safety:
// WG at step s observed all peers' s-1 tags => all peers >= s-1 => nobody still
// reads slot (s&3)'s old s-4 contents. Harness re-poisons ws (0xAAAA tag) so
// stale tags never match. Cell state fp32 in regs; h1[NT] published fp32.
__global__ __launch_bounds__(TPB, 1) void lstm_fused(
    const float* __restrict__ x,
    const float* __restrict__ wih0, const float* __restrict__ whh0,
    const float* __restrict__ bih0, const float* __restrict__ bhh0,
    const float* __restrict__ wih1, const float* __restrict__ whh1,
    const float* __restrict__ bih1, const float* __restrict__ bhh1,
    u32* __restrict__ ringA, u32* __restrict__ ringB,
    float* __restrict__ fb32)
{
  const int bid  = blockIdx.x;
  const int gr   = bid & 7;
  const int wg   = bid >> 3;
  const int j0   = wg * JS;
  const int tid  = threadIdx.x;
  const int wave = tid >> 6;
  const int lane = tid & 63;
  const int n    = lane & 15;        // A-frag row (batch) / B-frag col (j)
  const int q    = lane >> 4;        // k-sub-quad
  const int k0   = q * 8;

  __shared__ __align__(16) char smem[LDS_SZ];
  int* ctl = (int*)(smem + L_CTL);
  float* exgA = (float*)(smem + L_EXA);
  float* exgB = (float*)(smem + L_EXB);

  if (tid < 8) ctl[tid] = 0;

  // ---- init ring slot 0 = (tag=0, h=0) for own slice ----
  {
    int b_l = tid >> 4, j_l = tid & 15, jg = j0 + j_l;
    int wo = WIDX(jg, b_l);
    AT_ST(&ringA[RIX32(0, gr) + wo], 0u);
    AT_ST(&ringB[RIX32(0, gr) + wo], 0u);
  }
  __syncthreads();  // ctl visible; only __syncthreads in kernel

  const f4v z = {0.f, 0.f, 0.f, 0.f};
  const int p  = (wave & 1) * 64 + lane;  // pair-tid 0..127
  const int jq = p & 15, b0 = p >> 4;     // cells (b0,jq) and (b0+8,jq)
  const int jg = j0 + jq;
  const int ho0 = (jq >> 3) * 128 + b0 * 8 + (jq & 7);        // hout u32 idx
  const int ho1 = (jq >> 3) * 128 + (b0 + 8) * 8 + (jq & 7);
  const int slice = SLICE(wg);
  const int half = wave & 1;              // which half-plane this wave stages
  const ull TMASK = 0xFFFF0000FFFF0000ULL;

  if (wave < 2) {
    // ================= L0 pipeline (waves 0,1) =================
    const int g0 = wave * 2;  // gates g0, g0+1 (full K)
    s8v wx_h[2], wx_l[2];
#pragma unroll
    for (int i = 0; i < 2; ++i) {
      const float* wr = wih0 + (size_t)((g0 + i) * HDIM + j0 + n) * INDIM;
#pragma unroll
      for (int j = 0; j < 8; ++j) {
        int k = k0 + j;
        float v = (k < INDIM) ? wr[k] : 0.f;
        u16 hi = f2bf(v);
        wx_h[i][j] = (short)hi;
        wx_l[i][j] = (short)f2bf(v - bf2f(hi));
      }
    }
    s8v wh_h[2][16], wh_l[2][16];
#pragma unroll
    for (int i = 0; i < 2; ++i) {
      const float* wr = whh0 + (size_t)((g0 + i) * HDIM + j0 + n) * HDIM;
#pragma unroll
      for (int kt = 0; kt < 16; ++kt)
#pragma unroll
        for (int j = 0; j < 8; ++j) {
          float v = wr[kt * 32 + k0 + j];
          u16 hi = f2bf(v);
          wh_h[i][kt][j] = (short)hi;
          wh_l[i][kt][j] = (short)f2bf(v - bf2f(hi));
        }
    }
    float bias[4];
#pragma unroll
    for (int g = 0; g < 4; ++g) bias[g] = bih0[g * HDIM + jg] + bhh0[g * HDIM + jg];
    float c0a = 0.f, c0b = 0.f;
    int nbar = 0;

    for (int s = 1; s <= NT + 1; ++s) {
      // x-part (no peer dependency): before the data-poll
      f4v xa[2] = {z, z};
      if (s <= NT) {
        const float* xr = x + ((size_t)(gr * BG + n) * NT + (s - 1)) * INDIM;
        s8v axh, axl;
#pragma unroll
        for (int j = 0; j < 8; ++j) {
          int k = k0 + j;
          float v = (k < INDIM) ? xr[k] : 0.f;
          u16 hi = f2bf(v);
          axh[j] = (short)hi;
          axl[j] = (short)f2bf(v - bf2f(hi));
        }
#pragma unroll
        for (int i = 0; i < 2; ++i) {
          xa[i] = MFMA(axh, wx_h[i], xa[i]);
          xa[i] = MFMA(axl, wx_h[i], xa[i]);
          xa[i] = MFMA(axh, wx_l[i], xa[i]);
        }
      }
      // tag-poll + stage own half of h0[s-1] (slot (s-1)&3, tag s-1);
      // back-pressure: L1 must have finished step s-4 before LDS slot reuse
      const int sl3 = (s - 1) % 3;
      {
        const ull* src = (const ull*)(ringA + RIX32((s - 1) & 3, gr)) + half * 2048;
        const ull tg = (ull)(u16)(s - 1);
        const ull pat = (tg << 16) | (tg << 48);
        ull v[32];
        for (;;) {
          ull acc = 0;
#pragma unroll
          for (int i = 0; i < 16; ++i) {
            v[2 * i]     = AT_LD(src + (i * 64 + lane) * 2);
            v[2 * i + 1] = AT_LD(src + (i * 64 + lane) * 2 + 1);
          }
#pragma unroll
          for (int i = 0; i < 32; ++i) acc |= (v[i] ^ pat) & TMASK;
          int l1t = __hip_atomic_load(&ctl[7], __ATOMIC_ACQUIRE,
                                      __HIP_MEMORY_SCOPE_WORKGROUP);
          if (__ballot(acc == 0) == ~0ULL && l1t >= s - 4) break;
          __builtin_amdgcn_s_sleep(1);
        }
        char* dst = smem + L_H0 + sl3 * 16384 + half * 8192;
#pragma unroll
        for (int i = 0; i < 16; ++i) {
          ull a = v[2 * i], b = v[2 * i + 1];
          ull packed = (a & 0xFFFFULL) | ((a >> 16) & 0xFFFF0000ULL)
                     | ((b & 0xFFFFULL) << 32) | (((b >> 16) & 0xFFFF0000ULL) << 32);
          *(ull*)(dst + (i * 64 + lane) * 8) = packed;
        }
      }
      pbar(&ctl[0], nbar, lane);                              // P1: stage visible
      if (wave == 0 && lane == 0)
        __hip_atomic_store(&ctl[4 + sl3], s - 1, __ATOMIC_RELEASE,
                           __HIP_MEMORY_SCOPE_WORKGROUP);
      if (s == NT + 1) break;  // tail step only feeds L1's last x-input

      // K-loop: 16 ds_read_b128 + 64 MFMA (2 gates x 16kt x {Wh,Wl})
      const char* sh = smem + L_H0 + sl3 * 16384;
      f4v cHH[2] = {z, z}, cHL[2] = {z, z};
#pragma unroll
      for (int kt = 0; kt < 16; ++kt) {
        s8v ah = *(const s8v*)(sh + kt * 1024 + q * 256 + n * 16);
#pragma unroll
        for (int i = 0; i < 2; ++i) {
          cHH[i] = MFMA(ah, wh_h[i][kt], cHH[i]);
          cHL[i] = MFMA(ah, wh_l[i][kt], cHL[i]);
        }
      }
#pragma unroll
      for (int i = 0; i < 2; ++i) {
        f4v e = xa[i] + cHH[i] + cHL[i];
#pragma unroll
        for (int r = 0; r < 4; ++r)
          exgA[(g0 + i) * 256 + (q * 4 + r) * 16 + n] = e[r];
      }
      pbar(&ctl[0], nbar, lane);                              // P2: preacts ready
      // elementwise: 2 cells/thread -> (tag|h) into LDS hout
      u32* ho = (u32*)(smem + L_HOA);
      const u32 otag = ((u32)(u16)s) << 16;
      {
        float pi = exgA[0 * 256 + b0 * 16 + jq] + bias[0];
        float pf = exgA[1 * 256 + b0 * 16 + jq] + bias[1];
        float pg = exgA[2 * 256 + b0 * 16 + jq] + bias[2];
        float po = exgA[3 * 256 + b0 * 16 + jq] + bias[3];
        float ig = sigm(pi), fg = sigm(pf), gg = tanh_f(pg), og = sigm(po);
        c0a = fg * c0a + ig * gg;
        ho[ho0] = otag | (u32)f2bf(og * tanh_f(c0a));
      }
      {
        float pi = exgA[0 * 256 + (b0 + 8) * 16 + jq] + bias[0];
        float pf = exgA[1 * 256 + (b0 + 8) * 16 + jq] + bias[1];
        float pg = exgA[2 * 256 + (b0 + 8) * 16 + jq] + bias[2];
        float po = exgA[3 * 256 + (b0 + 8) * 16 + jq] + bias[3];
        float ig = sigm(pi), fg = sigm(pf), gg = tanh_f(pg), og = sigm(po);
        c0b = fg * c0b + ig * gg;
        ho[ho1] = otag | (u32)f2bf(og * tanh_f(c0b));
      }
      pbar(&ctl[0], nbar, lane);                              // P3: hout complete
      // both pair waves publish half each: no drain, no flag
      {
        ull v0 = *(const ull*)(smem + L_HOA + (half * 64 + lane) * 8);
        ull* d = (ull*)(ringA + RIX32(s & 3, gr) + slice);
        AT_ST(d + half * 64 + lane, v0);
      }
    }
  } else {
    // ================= L1 pipeline (waves 2,3) =================
    const int g0 = (wave - 2) * 2;  // gates g0, g0+1; wih1/whh1 hi-only
    s8v w1x[2][16], w1h[2][16];
#pragma unroll
    for (int i = 0; i < 2; ++i) {
      const float* p1 = wih1 + (size_t)((g0 + i) * HDIM + j0 + n) * HDIM;
      const float* p2 = whh1 + (size_t)((g0 + i) * HDIM + j0 + n) * HDIM;
#pragma unroll
      for (int kt = 0; kt < 16; ++kt)
#pragma unroll
        for (int j = 0; j < 8; ++j) {
          w1x[i][kt][j] = (short)f2bf(p1[kt * 32 + k0 + j]);
          w1h[i][kt][j] = (short)f2bf(p2[kt * 32 + k0 + j]);
        }
    }
    float bias[4];
#pragma unroll
    for (int g = 0; g < 4; ++g) bias[g] = bih1[g * HDIM + jg] + bhh1[g * HDIM + jg];
    float c1a = 0.f, c1b = 0.f;
    int nbar = 0;

    for (int t = 1; t <= NT; ++t) {
      // tag-poll + stage own half of h1[t-1] (slot (t-1)&3, tag t-1)
      {
        const ull* src = (const ull*)(ringB + RIX32((t - 1) & 3, gr)) + half * 2048;
        const ull tg = (ull)(u16)(t - 1);
        const ull pat = (tg << 16) | (tg << 48);
        ull v[32];
        for (;;) {
          ull acc = 0;
#pragma unroll
          for (int i = 0; i < 16; ++i) {
            v[2 * i]     = AT_LD(src + (i * 64 + lane) * 2);
            v[2 * i + 1] = AT_LD(src + (i * 64 + lane) * 2 + 1);
          }
#pragma unroll
          for (int i = 0; i < 32; ++i) acc |= (v[i] ^ pat) & TMASK;
          if (__ballot(acc == 0) == ~0ULL) break;
          __builtin_amdgcn_s_sleep(1);
        }
        char* dst = smem + L_H1 + half * 8192;
#pragma unroll
        for (int i = 0; i < 16; ++i) {
          ull a = v[2 * i], b = v[2 * i + 1];
          ull packed = (a & 0xFFFFULL) | ((a >> 16) & 0xFFFF0000ULL)
                     | ((b & 0xFFFFULL) << 32) | (((b >> 16) & 0xFFFF0000ULL) << 32);
          *(ull*)(dst + (i * 64 + lane) * 8) = packed;
        }
      }
      pbar(&ctl[1], nbar, lane);                              // Q1: h1 staged
      // K-loop B: h1 recurrence
      const char* th = smem + L_H1;
      f4v dHH[2] = {z, z};
#pragma unroll
      for (int kt = 0; kt < 16; ++kt) {
        s8v ah = *(const s8v*)(th + kt * 1024 + q * 256 + n * 16);
#pragma unroll
        for (int i = 0; i < 2; ++i) dHH[i] = MFMA(ah, w1h[i][kt], dHH[i]);
      }
      // wait for local L0's LDS stage of h0[t] (our x-input)
      const int sl3 = t % 3;
      while (__hip_atomic_load(&ctl[4 + sl3], __ATOMIC_ACQUIRE,
                               __HIP_MEMORY_SCOPE_WORKGROUP) < t) {}
      const char* sh = smem + L_H0 + sl3 * 16384;
      f4v eHH[2] = {z, z};
#pragma unroll
      for (int kt = 0; kt < 16; ++kt) {
        s8v ah = *(const s8v*)(sh + kt * 1024 + q * 256 + n * 16);
#pragma unroll
        for (int i = 0; i < 2; ++i) eHH[i] = MFMA(ah, w1x[i][kt], eHH[i]);
      }
#pragma unroll
      for (int i = 0; i < 2; ++i) {
        f4v e = dHH[i] + eHH[i];
#pragma unroll
        for (int r = 0; r < 4; ++r)
          exgB[(g0 + i) * 256 + (q * 4 + r) * 16 + n] = e[r];
      }
      pbar(&ctl[1], nbar, lane);                              // Q2: preacts ready
      u32* ho = (u32*)(smem + L_HOB);
      const u32 otag = ((u32)(u16)t) << 16;
      {
        float pi = exgB[0 * 256 + b0 * 16 + jq] + bias[0];
        float pf = exgB[1 * 256 + b0 * 16 + jq] + bias[1];
        float pg = exgB[2 * 256 + b0 * 16 + jq] + bias[2];
        float po = exgB[3 * 256 + b0 * 16 + jq] + bias[3];
        float ig = sigm(pi), fg = sigm(pf), gg = tanh_f(pg), og = sigm(po);
        c1a = fg * c1a + ig * gg;
        float h = og * tanh_f(c1a);
        ho[ho0] = otag | (u32)f2bf(h);
        if (t == NT)
          AT_ST((u32*)&fb32[(size_t)(gr * BG + b0) * HDIM + jg], __float_as_uint(h));
      }
      {
        float pi = exgB[0 * 256 + (b0 + 8) * 16 + jq] + bias[0];
        float pf = exgB[1 * 256 + (b0 + 8) * 16 + jq] + bias[1];
        float pg = exgB[2 * 256 + (b0 + 8) * 16 + jq] + bias[2];
        float po = exgB[3 * 256 + (b0 + 8) * 16 + jq] + bias[3];
        float ig = sigm(pi), fg = sigm(pf), gg = tanh_f(pg), og = sigm(po);
        c1b = fg * c1b + ig * gg;
        float h = og * tanh_f(c1b);
        ho[ho1] = otag | (u32)f2bf(h);
        if (t == NT)
          AT_ST((u32*)&fb32[(size_t)(gr * BG + b0 + 8) * HDIM + jg], __float_as_uint(h));
      }
      pbar(&ctl[1], nbar, lane);                              // Q3: hout complete
      {
        ull v0 = *(const ull*)(smem + L_HOB + (half * 64 + lane) * 8);
        ull* d = (ull*)(ringB + RIX32(t & 3, gr) + slice);
        AT_ST(d + half * 64 + lane, v0);
      }
      if (wave == 2 && lane == 0)
        __hip_atomic_store(&ctl[7], t, __ATOMIC_RELEASE,
                           __HIP_MEMORY_SCOPE_WORKGROUP);  // local back-pressure
    }
  }
}

// ---------------- final linear: out = h1[NT] @ lin_w^T + lin_b (fp32 h) ------
__global__ void final_linear(const float* __restrict__ fb32,
                             const float* __restrict__ lin_w,
                             const float* __restrict__ lin_b,
                             float* __restrict__ out) {
  int b = blockIdx.x, o = threadIdx.x;
  if (o < OUTDIM) {
    float acc = lin_b[o];
    const u32* hr = (const u32*)(fb32 + (size_t)b * HDIM);
    for (int j = 0; j < HDIM; ++j) {
      float h = __uint_as_float(AT_LD(hr + j));  // sc1: bypass any stale L2 line
      acc += h * lin_w[(size_t)o * HDIM + j];
    }
    out[b * OUTDIM + o] = acc;
  }
}

__global__ void sentinel_kernel(float* __restrict__ out, int nv) {
  int i = blockIdx.x * TPB + threadIdx.x;
  if (i < nv) out[i] = 1e30f;
}

extern "C" void kernel_launch(void* const* d_in, const int* in_sizes, int n_in,
                              void* d_out, int out_size, void* d_ws, size_t ws_size,
                              hipStream_t stream) {
  (void)in_sizes; (void)n_in;
  const float* x     = (const float*)d_in[0];
  const float* wih0  = (const float*)d_in[1];
  const float* whh0  = (const float*)d_in[2];
  const float* bih0  = (const float*)d_in[3];
  const float* bhh0  = (const float*)d_in[4];
  const float* wih1  = (const float*)d_in[5];
  const float* whh1  = (const float*)d_in[6];
  const float* bih1  = (const float*)d_in[7];
  const float* bhh1  = (const float*)d_in[8];
  const float* lin_w = (const float*)d_in[9];
  const float* lin_b = (const float*)d_in[10];
  float* out = (float*)d_out;
  char* ws = (char*)d_ws;

  if (ws_size < WS_NEEDED) {
    sentinel_kernel<<<(out_size + TPB - 1) / TPB, TPB, 0, stream>>>(out, out_size);
    return;
  }

  u32* ringA  = (u32*)(ws + RA_OFF);
  u32* ringB  = (u32*)(ws + RB_OFF);
  float* fb32 = (float*)(ws + FB32_OFF);

  lstm_fused<<<256, TPB, 0, stream>>>(x, wih0, whh0, bih0, bhh0,
                                      wih1, whh1, bih1, bhh1,
                                      ringA, ringB, fb32);
  final_linear<<<BTOT, 64, 0, stream>>>(fb32, lin_w, lin_b, out);
}